// Round 5
// baseline (153.709 us; speedup 1.0000x reference)
//
#include <hip/hip_runtime.h>
#include <hip/hip_bf16.h>

// 1-NN VQ via split-bf16 MFMA + exact fp32 refinement.
//   score[q][k] = csq[k] - 2*dot(q,c_k); out = argmin_k (lowest-k tie-break).
// Phase 0 (knn_prep): codebook -> bf16 hi/lo fragment-ready cbB (kb-major) + csq.
// Phase A (knn_mfma): PERSISTENT-CODEBOOK rewrite (r14).
//   r13 counters: WRITE_SIZE 68->4.6 MB (r10 spill theory CONFIRMED), mfma
//   134->51 us warm. But MfmaUtil 18%, HBM 793 GB/s (10%), Occupancy 18% ->
//   latency/structure-bound: 1024 blocks each re-staged the whole 128 KB
//   codebook (128 MB L2->LDS) through 4 barrier-serialized phases.
//   r14: whole split codebook (128 KB) fits LDS (160 KB/CU). One 512-thread
//   block per CU (grid=256, launch_bounds(512,2), 128 KB static LDS -- same
//   config as guide's verified 8-phase template). B filled ONCE (16 x
//   global_load_lds width=16 per wave), ONE __syncthreads, then 2 batches of
//   256 q whose K-loop is pure ds_read_b128+MFMA from immutable LDS: zero
//   steady-state barriers, zero re-staging (B L2 traffic 128->32 MB). Waves
//   independent after fill; odd waves take batches in reverse order
//   (bt ^ (wave&1)) so the 2 waves/SIMD run in antiphase: one wave's HBM
//   A-load burst overlaps the other's K-loop.
//   Per wave per batch: 2 m-tiles x 16 n-tiles (acc[2][16]=128 AGPR), A
//   split-converted once into regs (ah/al[2][4]=64 VGPR); dot ~= qh.ch +
//   ql.ch + qh.cl (3-product, score err ~1.9e-3); per-wave top-2 over all
//   256 codes; gap < T=0.004 -> worklist.
// Phase B (knn_refine): exact fp32 rescan, block-per-query.
// Reg budget: 128 AGPR + ~110 VGPR ~= 238 <= 256 (2 waves/EU cap) -> no spill.

typedef __bf16 bf16x8 __attribute__((ext_vector_type(8)));
typedef float  floatx4 __attribute__((ext_vector_type(4)));

#define MFMA16 __builtin_amdgcn_mfma_f32_16x16x32_bf16

#define CNT_OFF 0
#define CSQ_OFF 1024
#define CBB_OFF 4096
#define WL_OFF  (4096 + 131072)
#define WL_CAP  32768
#define T_FLAG  0.004f

typedef __attribute__((address_space(1))) const unsigned int gu32;
typedef __attribute__((address_space(3))) unsigned int lu32;

__device__ __forceinline__ unsigned fmap(float f) {
    unsigned u = __float_as_uint(f);
    return (u & 0x80000000u) ? ~u : (u | 0x80000000u);
}
__device__ __forceinline__ float unfmap(unsigned u) {
    unsigned b = (u & 0x80000000u) ? (u ^ 0x80000000u) : ~u;
    return __uint_as_float(b);
}

// ---------------- Phase 0: codebook split, kb-major fragment layout, csq ----------------
// cbB element index = ((kb*16 + t)*2 + part)*512 + ln*8 + j   (= id*8 below)
//   kb = k-chunk 0..3; t = ntile 0..15; part: 0=hi 1=lo;
//   lane ln: n = t*16 + (ln&15), k = kb*32 + (ln>>4)*8 + j.
__global__ void knn_prep(const float* __restrict__ cb, __bf16* __restrict__ cbB,
                         float* __restrict__ csq, int* __restrict__ cnt) {
    const int tid = threadIdx.x;
    const int id = blockIdx.x * 256 + tid;       // 0..8191
    if (id == 0) *cnt = 0;
    const int ln = id & 63;
    const int part = (id >> 6) & 1;
    const int step = id >> 7;                    // kb*16 + t
    const int t4 = step & 15;
    const int kb = step >> 4;
    const int n = t4 * 16 + (ln & 15);
    const int k0 = kb * 32 + (ln >> 4) * 8;
    const float* src = cb + (size_t)n * 128 + k0;
    union { __bf16 h[8]; uint4 u; } p;
#pragma unroll
    for (int j = 0; j < 8; ++j) {
        float f = src[j];
        __bf16 hh = (__bf16)f;
        p.h[j] = (part == 0) ? hh : (__bf16)(f - (float)hh);
    }
    *(uint4*)(cbB + (size_t)id * 8) = p.u;

    if (blockIdx.x == 0) {
        const float4* row = (const float4*)(cb + (size_t)tid * 128);
        float a0 = 0.f, a1 = 0.f, a2 = 0.f, a3 = 0.f;
#pragma unroll 8
        for (int j = 0; j < 32; ++j) {
            float4 v = row[j];
            a0 = fmaf(v.x, v.x, a0);
            a1 = fmaf(v.y, v.y, a1);
            a2 = fmaf(v.z, v.z, a2);
            a3 = fmaf(v.w, v.w, a3);
        }
        csq[tid] = (a0 + a1) + (a2 + a3);
    }
}

// ---------------- Phase A: persistent-codebook MFMA scores + top-2 + flag ----------------
__global__ __launch_bounds__(512, 2) void knn_mfma(const float* __restrict__ x,
                                                   const __bf16* __restrict__ cbB,
                                                   const float* __restrict__ csq_g,
                                                   int* __restrict__ out,
                                                   int* __restrict__ cnt,
                                                   int* __restrict__ wl) {
    __shared__ __bf16 sB[65536];                 // 128 KB: ENTIRE split codebook

    const int tid = threadIdx.x;
    const int wave = tid >> 6;                   // 0..7
    const int lane = tid & 63;
    const int rl = lane & 15;                    // m/n col within tile
    const int kg = lane >> 4;                    // k-group 0..3

    // ---- one-time B fill: wave w copies 16 KB (16 x 1 KB, linear) ----
    {
        const char* gsrc = (const char*)cbB + wave * 16384 + lane * 16;
        char* ldst = (char*)sB + wave * 16384;
#pragma unroll
        for (int i = 0; i < 16; ++i)
            __builtin_amdgcn_global_load_lds((gu32*)(gsrc + i * 1024),
                                             (lu32*)(ldst + i * 1024), 16, 0, 0);
    }

    // ---- 2 batches of 256 q; odd waves in reverse order (antiphase per SIMD) ----
#pragma unroll
    for (int bt = 0; bt < 2; ++bt) {
        const int be = bt ^ (wave & 1);          // this wave's batch index
        const size_t q0 = ((size_t)blockIdx.x * 2 + be) * 256 + wave * 32;

        // ---- A: load + split-convert this wave's 2 m-tiles into registers ----
        const float* xq = x + q0 * 128;
        bf16x8 ah[2][4], al[2][4];
#pragma unroll
        for (int m = 0; m < 2; ++m) {
#pragma unroll
            for (int kb = 0; kb < 4; ++kb) {
                const float* s = xq + (size_t)(m * 16 + rl) * 128 + kb * 32 + kg * 8;
                float4 f0 = *(const float4*)(s);
                float4 f1 = *(const float4*)(s + 4);
                float f[8] = {f0.x, f0.y, f0.z, f0.w, f1.x, f1.y, f1.z, f1.w};
                union { __bf16 h[8]; bf16x8 v; } ph, pl;
#pragma unroll
                for (int j = 0; j < 8; ++j) {
                    __bf16 hh = (__bf16)f[j];
                    ph.h[j] = hh;
                    pl.h[j] = (__bf16)(f[j] - (float)hh);
                }
                ah[m][kb] = ph.v;
                al[m][kb] = pl.v;
            }
        }

        floatx4 acc[2][16];
#pragma unroll
        for (int m = 0; m < 2; ++m)
#pragma unroll
            for (int t = 0; t < 16; ++t) acc[m][t] = (floatx4){0.f, 0.f, 0.f, 0.f};

        if (bt == 0) __syncthreads();            // B fill landed (vmcnt drain), once

        // ---- K-loop: pure LDS reads + MFMA, no barriers ----
        // element offset = kb*16384 + t*1024 + part*512 + lane*8
#pragma unroll
        for (int kb = 0; kb < 4; ++kb) {
            const __bf16* sbase = sB + kb * 16384 + lane * 8;
#pragma unroll
            for (int t = 0; t < 16; ++t) {
                bf16x8 bh = *(const bf16x8*)(sbase + t * 1024);
                bf16x8 bl = *(const bf16x8*)(sbase + t * 1024 + 512);
                acc[0][t] = MFMA16(ah[0][kb], bh, acc[0][t], 0, 0, 0);
                acc[1][t] = MFMA16(ah[1][kb], bh, acc[1][t], 0, 0, 0);
                acc[0][t] = MFMA16(al[0][kb], bh, acc[0][t], 0, 0, 0);
                acc[1][t] = MFMA16(al[1][kb], bh, acc[1][t], 0, 0, 0);
                acc[0][t] = MFMA16(ah[0][kb], bl, acc[0][t], 0, 0, 0);
                acc[1][t] = MFMA16(ah[1][kb], bl, acc[1][t], 0, 0, 0);
            }
        }

        // ---- epilogue: per-wave top-2 over ALL 256 codes ----
        float cs[16];
#pragma unroll
        for (int t = 0; t < 16; ++t) cs[t] = csq_g[t * 16 + rl];   // L1-hot

#pragma unroll
        for (int m = 0; m < 2; ++m) {
#pragma unroll
            for (int r = 0; r < 4; ++r) {
                unsigned long long b = ~0ULL, s = ~0ULL;
#pragma unroll
                for (int t = 0; t < 16; ++t) {
                    const int n = t * 16 + rl;
                    float score = fmaf(-2.0f, acc[m][t][r], cs[t]);
                    unsigned long long key =
                        ((unsigned long long)fmap(score) << 32) | (unsigned)n;
                    if (key < b) { s = b; b = key; }
                    else if (key < s) { s = key; }
                }
#pragma unroll
                for (int d = 1; d < 16; d <<= 1) {
                    unsigned long long ob = __shfl_xor(b, d);
                    unsigned long long os = __shfl_xor(s, d);
                    unsigned long long nb = ob < b ? ob : b;
                    unsigned long long mx = ob < b ? b : ob;
                    unsigned long long mn = os < s ? os : s;
                    b = nb;
                    s = mx < mn ? mx : mn;
                }
                if (rl == 0) {
                    const size_t qg = q0 + m * 16 + kg * 4 + r;
                    out[qg] = (int)(unsigned)(b & 0xFFFFFFFFull);
                    float f1 = unfmap((unsigned)(b >> 32));
                    float f2 = unfmap((unsigned)(s >> 32));
                    if (f2 - f1 < T_FLAG) {
                        int idx = atomicAdd(cnt, 1);
                        if (idx < WL_CAP) wl[idx] = (int)qg;
                    }
                }
            }
        }
    }
}

// ---------------- Phase B: exact fp32 rescan, block-per-query ----------------
__global__ __launch_bounds__(256) void knn_refine(const float* __restrict__ x,
                                                  const float* __restrict__ cb,
                                                  const float* __restrict__ csq_g,
                                                  const int* __restrict__ wl,
                                                  const int* __restrict__ cnt,
                                                  int* __restrict__ out) {
    __shared__ unsigned long long sP[4];
    const int tid = threadIdx.x;           // == code index k
    const int lane = tid & 63;
    const int wave = tid >> 6;

    int n = *cnt;
    if (n > WL_CAP) n = WL_CAP;
    const float mycsq = csq_g[tid];
    const float4* cr = (const float4*)(cb + (size_t)tid * 128);

    for (int i = blockIdx.x; i < n; i += gridDim.x) {
        const int q = wl[i];
        const float4* qr = (const float4*)(x + (size_t)q * 128);
        float a0 = 0.f, a1 = 0.f, a2 = 0.f, a3 = 0.f;
#pragma unroll 8
        for (int c4 = 0; c4 < 32; ++c4) {
            float4 qv = qr[c4];            // broadcast (same addr all lanes)
            float4 cv = cr[c4];
            a0 = fmaf(qv.x, cv.x, a0);
            a1 = fmaf(qv.y, cv.y, a1);
            a2 = fmaf(qv.z, cv.z, a2);
            a3 = fmaf(qv.w, cv.w, a3);
        }
        float dot = (a0 + a1) + (a2 + a3);
        float score = fmaf(-2.0f, dot, mycsq);
        unsigned long long key =
            ((unsigned long long)fmap(score) << 32) | (unsigned)tid;
#pragma unroll
        for (int d = 1; d < 64; d <<= 1) {
            unsigned long long o = __shfl_xor(key, d);
            key = o < key ? o : key;
        }
        if (lane == 0) sP[wave] = key;
        __syncthreads();
        if (tid == 0) {
            unsigned long long b = sP[0];
            unsigned long long o;
            o = sP[1]; b = o < b ? o : b;
            o = sP[2]; b = o < b ? o : b;
            o = sP[3]; b = o < b ? o : b;
            out[q] = (int)(unsigned)(b & 0xFFFFFFFFull);
        }
        __syncthreads();
    }
}

extern "C" void kernel_launch(void* const* d_in, const int* in_sizes, int n_in,
                              void* d_out, int out_size, void* d_ws, size_t ws_size,
                              hipStream_t stream) {
    const float* x = (const float*)d_in[0];
    const float* cb = (const float*)d_in[1];
    int* out = (int*)d_out;

    char* ws = (char*)d_ws;
    int* cnt = (int*)(ws + CNT_OFF);
    float* csq = (float*)(ws + CSQ_OFF);
    __bf16* cbB = (__bf16*)(ws + CBB_OFF);
    int* wl = (int*)(ws + WL_OFF);

    const int M = in_sizes[0] / 128;     // 131072

    knn_prep<<<32, 256, 0, stream>>>(cb, cbB, csq, cnt);
    knn_mfma<<<M / 512, 512, 0, stream>>>(x, cbB, csq, out, cnt, wl);
    knn_refine<<<240, 256, 0, stream>>>(x, cb, csq, wl, cnt, out);
}

// Round 6
// 148.433 us; speedup vs baseline: 1.0355x; 1.0355x over previous
//
#include <hip/hip_runtime.h>
#include <hip/hip_bf16.h>

// 1-NN VQ via split-bf16 MFMA + exact fp32 refinement.
//   score[q][k] = csq[k] - 2*dot(q,c_k); out = argmin_k (lowest-k tie-break).
// Phase 0 (knn_prep): codebook -> bf16 hi/lo fragment-ready cbB (kb-major) + csq.
// Phase A (knn_mfma): persistent-codebook (r14) + r15 fixes.
//   r14 counters: WRITE_SIZE 4.6->28.7 MB (spill AGAIN): #pragma unroll on the
//   bt loop hoisted batch-1's 16 global A-loads (64 VGPR) over batch-0's
//   epilogue -> ~300 live > 256 cap -> ~45 dw/thread scratch; dur 51->68 us.
//   r15: (a) unroll 1 on bt loop -- single-batch live set ~240 <= 256;
//   (b) antiphase fixed: SIMD pairs waves {w,w+4}, so use bt^((wave>>2)&1)
//   (r14's bt^(wave&1) gave SAME parity per SIMD -> no overlap);
//   (c) epilogue switched to float-domain top-2 (no 64-bit fmap keys): any
//   tie -> gap~0 < T -> refine rescans exactly with index tie-break, so the
//   approx pass needs no deterministic tie handling. ~6 instr/candidate vs
//   ~20 -> epilogue VALU ~6000->~2100 cyc/wave (VALUBusy was 25-35%);
//   (d) cs[] hoisted out of batch loop.
//   Structure: 1 block/CU (grid=256, 512 thr, 128 KB LDS = whole split
//   codebook, filled once via 16x global_load_lds w=16/wave, ONE barrier);
//   2 batches x 256 q; K-loop pure ds_read_b128+MFMA, zero steady barriers.
//   Per wave per batch: 2 m-tiles x 16 n-tiles (acc[2][16]=128 AGPR), A
//   split-converted once (ah/al[2][4]=64 VGPR); dot ~= qh.ch+ql.ch+qh.cl
//   (3-product, score err ~1.9e-3); top-2 gap < T=0.004 -> worklist.
// Phase B (knn_refine): exact fp32 rescan (u64 keys, lowest-k tie-break).

typedef __bf16 bf16x8 __attribute__((ext_vector_type(8)));
typedef float  floatx4 __attribute__((ext_vector_type(4)));

#define MFMA16 __builtin_amdgcn_mfma_f32_16x16x32_bf16

#define CNT_OFF 0
#define CSQ_OFF 1024
#define CBB_OFF 4096
#define WL_OFF  (4096 + 131072)
#define WL_CAP  32768
#define T_FLAG  0.004f

typedef __attribute__((address_space(1))) const unsigned int gu32;
typedef __attribute__((address_space(3))) unsigned int lu32;

__device__ __forceinline__ unsigned fmap(float f) {
    unsigned u = __float_as_uint(f);
    return (u & 0x80000000u) ? ~u : (u | 0x80000000u);
}

// ---------------- Phase 0: codebook split, kb-major fragment layout, csq ----------------
// cbB element index = ((kb*16 + t)*2 + part)*512 + ln*8 + j   (= id*8 below)
//   kb = k-chunk 0..3; t = ntile 0..15; part: 0=hi 1=lo;
//   lane ln: n = t*16 + (ln&15), k = kb*32 + (ln>>4)*8 + j.
__global__ void knn_prep(const float* __restrict__ cb, __bf16* __restrict__ cbB,
                         float* __restrict__ csq, int* __restrict__ cnt) {
    const int tid = threadIdx.x;
    const int id = blockIdx.x * 256 + tid;       // 0..8191
    if (id == 0) *cnt = 0;
    const int ln = id & 63;
    const int part = (id >> 6) & 1;
    const int step = id >> 7;                    // kb*16 + t
    const int t4 = step & 15;
    const int kb = step >> 4;
    const int n = t4 * 16 + (ln & 15);
    const int k0 = kb * 32 + (ln >> 4) * 8;
    const float* src = cb + (size_t)n * 128 + k0;
    union { __bf16 h[8]; uint4 u; } p;
#pragma unroll
    for (int j = 0; j < 8; ++j) {
        float f = src[j];
        __bf16 hh = (__bf16)f;
        p.h[j] = (part == 0) ? hh : (__bf16)(f - (float)hh);
    }
    *(uint4*)(cbB + (size_t)id * 8) = p.u;

    if (blockIdx.x == 0) {
        const float4* row = (const float4*)(cb + (size_t)tid * 128);
        float a0 = 0.f, a1 = 0.f, a2 = 0.f, a3 = 0.f;
#pragma unroll 8
        for (int j = 0; j < 32; ++j) {
            float4 v = row[j];
            a0 = fmaf(v.x, v.x, a0);
            a1 = fmaf(v.y, v.y, a1);
            a2 = fmaf(v.z, v.z, a2);
            a3 = fmaf(v.w, v.w, a3);
        }
        csq[tid] = (a0 + a1) + (a2 + a3);
    }
}

// ---------------- Phase A: persistent-codebook MFMA scores + top-2 + flag ----------------
__global__ __launch_bounds__(512, 2) void knn_mfma(const float* __restrict__ x,
                                                   const __bf16* __restrict__ cbB,
                                                   const float* __restrict__ csq_g,
                                                   int* __restrict__ out,
                                                   int* __restrict__ cnt,
                                                   int* __restrict__ wl) {
    __shared__ __bf16 sB[65536];                 // 128 KB: ENTIRE split codebook

    const int tid = threadIdx.x;
    const int wave = tid >> 6;                   // 0..7
    const int lane = tid & 63;
    const int rl = lane & 15;                    // m/n col within tile
    const int kg = lane >> 4;                    // k-group 0..3

    // ---- one-time B fill: wave w copies 16 KB (16 x 1 KB, linear) ----
    {
        const char* gsrc = (const char*)cbB + wave * 16384 + lane * 16;
        char* ldst = (char*)sB + wave * 16384;
#pragma unroll
        for (int i = 0; i < 16; ++i)
            __builtin_amdgcn_global_load_lds((gu32*)(gsrc + i * 1024),
                                             (lu32*)(ldst + i * 1024), 16, 0, 0);
    }

    float cs[16];
#pragma unroll
    for (int t = 0; t < 16; ++t) cs[t] = csq_g[t * 16 + rl];   // L1-hot, once

    // ---- 2 batches of 256 q; SIMD-paired waves {w,w+4} in antiphase ----
#pragma unroll 1
    for (int bt = 0; bt < 2; ++bt) {
        const int be = bt ^ ((wave >> 2) & 1);   // this wave's batch index
        const size_t q0 = ((size_t)blockIdx.x * 2 + be) * 256 + wave * 32;

        // ---- A: load + split-convert this wave's 2 m-tiles into registers ----
        const float* xq = x + q0 * 128;
        bf16x8 ah[2][4], al[2][4];
#pragma unroll
        for (int m = 0; m < 2; ++m) {
#pragma unroll
            for (int kb = 0; kb < 4; ++kb) {
                const float* s = xq + (size_t)(m * 16 + rl) * 128 + kb * 32 + kg * 8;
                float4 f0 = *(const float4*)(s);
                float4 f1 = *(const float4*)(s + 4);
                float f[8] = {f0.x, f0.y, f0.z, f0.w, f1.x, f1.y, f1.z, f1.w};
                union { __bf16 h[8]; bf16x8 v; } ph, pl;
#pragma unroll
                for (int j = 0; j < 8; ++j) {
                    __bf16 hh = (__bf16)f[j];
                    ph.h[j] = hh;
                    pl.h[j] = (__bf16)(f[j] - (float)hh);
                }
                ah[m][kb] = ph.v;
                al[m][kb] = pl.v;
            }
        }

        floatx4 acc[2][16];
#pragma unroll
        for (int m = 0; m < 2; ++m)
#pragma unroll
            for (int t = 0; t < 16; ++t) acc[m][t] = (floatx4){0.f, 0.f, 0.f, 0.f};

        if (bt == 0) __syncthreads();            // B fill landed (vmcnt drain), once

        // ---- K-loop: pure LDS reads + MFMA, no barriers ----
        // element offset = kb*16384 + t*1024 + part*512 + lane*8
#pragma unroll
        for (int kb = 0; kb < 4; ++kb) {
            const __bf16* sbase = sB + kb * 16384 + lane * 8;
#pragma unroll
            for (int t = 0; t < 16; ++t) {
                bf16x8 bh = *(const bf16x8*)(sbase + t * 1024);
                bf16x8 bl = *(const bf16x8*)(sbase + t * 1024 + 512);
                acc[0][t] = MFMA16(ah[0][kb], bh, acc[0][t], 0, 0, 0);
                acc[1][t] = MFMA16(ah[1][kb], bh, acc[1][t], 0, 0, 0);
                acc[0][t] = MFMA16(al[0][kb], bh, acc[0][t], 0, 0, 0);
                acc[1][t] = MFMA16(al[1][kb], bh, acc[1][t], 0, 0, 0);
                acc[0][t] = MFMA16(ah[0][kb], bl, acc[0][t], 0, 0, 0);
                acc[1][t] = MFMA16(ah[1][kb], bl, acc[1][t], 0, 0, 0);
            }
        }

        // ---- epilogue: float-domain per-wave top-2 (ties -> refine) ----
#pragma unroll
        for (int m = 0; m < 2; ++m) {
#pragma unroll
            for (int r = 0; r < 4; ++r) {
                float bf = __builtin_inff(), sf = __builtin_inff();
                int bi = 0;
#pragma unroll
                for (int t = 0; t < 16; ++t) {
                    const float sc = fmaf(-2.0f, acc[m][t][r], cs[t]);
                    const bool lt = sc < bf;
                    sf = lt ? bf : fminf(sf, sc);
                    bf = lt ? sc : bf;
                    bi = lt ? (t * 16 + rl) : bi;
                }
#pragma unroll
                for (int d = 1; d < 16; d <<= 1) {
                    const float obf = __shfl_xor(bf, d);
                    const int   obi = __shfl_xor(bi, d);
                    const float osf = __shfl_xor(sf, d);
                    const bool lt = obf < bf;
                    const float loser = lt ? bf : obf;       // larger best
                    sf = fminf(fminf(sf, osf), loser);
                    bf = lt ? obf : bf;
                    bi = lt ? obi : bi;
                }
                if (rl == 0) {
                    const size_t qg = q0 + m * 16 + kg * 4 + r;
                    out[qg] = bi;
                    if (sf - bf < T_FLAG) {      // gap small (or tie) -> exact pass
                        int idx = atomicAdd(cnt, 1);
                        if (idx < WL_CAP) wl[idx] = (int)qg;
                    }
                }
            }
        }
    }
}

// ---------------- Phase B: exact fp32 rescan, block-per-query ----------------
__global__ __launch_bounds__(256) void knn_refine(const float* __restrict__ x,
                                                  const float* __restrict__ cb,
                                                  const float* __restrict__ csq_g,
                                                  const int* __restrict__ wl,
                                                  const int* __restrict__ cnt,
                                                  int* __restrict__ out) {
    __shared__ unsigned long long sP[4];
    const int tid = threadIdx.x;           // == code index k
    const int lane = tid & 63;
    const int wave = tid >> 6;

    int n = *cnt;
    if (n > WL_CAP) n = WL_CAP;
    const float mycsq = csq_g[tid];
    const float4* cr = (const float4*)(cb + (size_t)tid * 128);

    for (int i = blockIdx.x; i < n; i += gridDim.x) {
        const int q = wl[i];
        const float4* qr = (const float4*)(x + (size_t)q * 128);
        float a0 = 0.f, a1 = 0.f, a2 = 0.f, a3 = 0.f;
#pragma unroll 8
        for (int c4 = 0; c4 < 32; ++c4) {
            float4 qv = qr[c4];            // broadcast (same addr all lanes)
            float4 cv = cr[c4];
            a0 = fmaf(qv.x, cv.x, a0);
            a1 = fmaf(qv.y, cv.y, a1);
            a2 = fmaf(qv.z, cv.z, a2);
            a3 = fmaf(qv.w, cv.w, a3);
        }
        float dot = (a0 + a1) + (a2 + a3);
        float score = fmaf(-2.0f, dot, mycsq);
        unsigned long long key =
            ((unsigned long long)fmap(score) << 32) | (unsigned)tid;
#pragma unroll
        for (int d = 1; d < 64; d <<= 1) {
            unsigned long long o = __shfl_xor(key, d);
            key = o < key ? o : key;
        }
        if (lane == 0) sP[wave] = key;
        __syncthreads();
        if (tid == 0) {
            unsigned long long b = sP[0];
            unsigned long long o;
            o = sP[1]; b = o < b ? o : b;
            o = sP[2]; b = o < b ? o : b;
            o = sP[3]; b = o < b ? o : b;
            out[q] = (int)(unsigned)(b & 0xFFFFFFFFull);
        }
        __syncthreads();
    }
}

extern "C" void kernel_launch(void* const* d_in, const int* in_sizes, int n_in,
                              void* d_out, int out_size, void* d_ws, size_t ws_size,
                              hipStream_t stream) {
    const float* x = (const float*)d_in[0];
    const float* cb = (const float*)d_in[1];
    int* out = (int*)d_out;

    char* ws = (char*)d_ws;
    int* cnt = (int*)(ws + CNT_OFF);
    float* csq = (float*)(ws + CSQ_OFF);
    __bf16* cbB = (__bf16*)(ws + CBB_OFF);
    int* wl = (int*)(ws + WL_OFF);

    const int M = in_sizes[0] / 128;     // 131072

    knn_prep<<<32, 256, 0, stream>>>(cb, cbB, csq, cnt);
    knn_mfma<<<M / 512, 512, 0, stream>>>(x, cbB, csq, out, cnt, wl);
    knn_refine<<<240, 256, 0, stream>>>(x, cb, csq, wl, cnt, out);
}

// Round 7
// 134.325 us; speedup vs baseline: 1.1443x; 1.1050x over previous
//
#include <hip/hip_runtime.h>
#include <hip/hip_bf16.h>

// 1-NN VQ via split-bf16 MFMA + exact fp32 refinement.
//   score[q][k] = csq[k] - 2*dot(q,c_k); out = argmin_k (lowest-k tie-break).
// Phase 0 (knn_prep): codebook -> bf16 hi/lo fragment-ready cbB (kb-major) + csq.
// Phase A (knn_mfma): persistent codebook, SPILL-PROOF config (r16).
//   Spill history: r10 (direct-global B, 68 MB scratch), r14 (unroll-hoisted
//   A-loads, 28.7 MB), r15 (unroll-1 + float epilogue, STILL 48.6 MB, ~84
//   dw/thread). Root cause: at (512thr, 2 waves/EU) the unified file caps at
//   256/wave = 128 AGPR (acc) + 128 arch; arch live (ah/al 64 + ds_read
//   prefetch + cs + temps) > 128 under any aggressive schedule, and the
//   allocator spills ACC SLICES (live across whole loop) -> re-read/written
//   24x/batch in the K-loop -> tens of MB of scratch traffic.
//   r16: 1 wave/SIMD with 512-reg budget: 256-thread blocks (4 waves),
//   launch_bounds(256,1), grid=256 (1 block/CU; 128 KB LDS forces it anyway).
//   Unified demand ~350 << 512 -> scheduler free, spill impossible. Lost TLP
//   covered by ILP: fully-unrolled K-loop has 32 independent 3-deep MFMA
//   chains per kb; per-CU per batch MFMA 1920 cyc || LDS 2048 cyc -> ~50%
//   MfmaUtil ceiling; A-latency + epilogue exposed per batch -> ~8-9 us/SIMD,
//   near x's 10 us HBM floor.
//   Structure: whole split codebook (128 KB) in LDS, filled once (32 x
//   global_load_lds w=16 per wave), ONE barrier ever; 4 batches x 32 q/wave;
//   K-loop pure ds_read_b128+MFMA. Per batch: acc[2][16]=128 AGPR, A
//   split-converted once (ah/al[2][4]=64 VGPR); dot ~= qh.ch+ql.ch+qh.cl
//   (3-product, score err ~1.9e-3); float-domain top-2 (r15: VALUBusy
//   25->17%, keep), gap < T=0.004 -> worklist (ties -> refine's exact pass).
// Phase B (knn_refine): exact fp32 rescan (u64 keys, lowest-k tie-break).

typedef __bf16 bf16x8 __attribute__((ext_vector_type(8)));
typedef float  floatx4 __attribute__((ext_vector_type(4)));

#define MFMA16 __builtin_amdgcn_mfma_f32_16x16x32_bf16

#define CNT_OFF 0
#define CSQ_OFF 1024
#define CBB_OFF 4096
#define WL_OFF  (4096 + 131072)
#define WL_CAP  32768
#define T_FLAG  0.004f

typedef __attribute__((address_space(1))) const unsigned int gu32;
typedef __attribute__((address_space(3))) unsigned int lu32;

__device__ __forceinline__ unsigned fmap(float f) {
    unsigned u = __float_as_uint(f);
    return (u & 0x80000000u) ? ~u : (u | 0x80000000u);
}

// ---------------- Phase 0: codebook split, kb-major fragment layout, csq ----------------
// cbB element index = ((kb*16 + t)*2 + part)*512 + ln*8 + j   (= id*8 below)
//   kb = k-chunk 0..3; t = ntile 0..15; part: 0=hi 1=lo;
//   lane ln: n = t*16 + (ln&15), k = kb*32 + (ln>>4)*8 + j.
__global__ void knn_prep(const float* __restrict__ cb, __bf16* __restrict__ cbB,
                         float* __restrict__ csq, int* __restrict__ cnt) {
    const int tid = threadIdx.x;
    const int id = blockIdx.x * 256 + tid;       // 0..8191
    if (id == 0) *cnt = 0;
    const int ln = id & 63;
    const int part = (id >> 6) & 1;
    const int step = id >> 7;                    // kb*16 + t
    const int t4 = step & 15;
    const int kb = step >> 4;
    const int n = t4 * 16 + (ln & 15);
    const int k0 = kb * 32 + (ln >> 4) * 8;
    const float* src = cb + (size_t)n * 128 + k0;
    union { __bf16 h[8]; uint4 u; } p;
#pragma unroll
    for (int j = 0; j < 8; ++j) {
        float f = src[j];
        __bf16 hh = (__bf16)f;
        p.h[j] = (part == 0) ? hh : (__bf16)(f - (float)hh);
    }
    *(uint4*)(cbB + (size_t)id * 8) = p.u;

    if (blockIdx.x == 0) {
        const float4* row = (const float4*)(cb + (size_t)tid * 128);
        float a0 = 0.f, a1 = 0.f, a2 = 0.f, a3 = 0.f;
#pragma unroll 8
        for (int j = 0; j < 32; ++j) {
            float4 v = row[j];
            a0 = fmaf(v.x, v.x, a0);
            a1 = fmaf(v.y, v.y, a1);
            a2 = fmaf(v.z, v.z, a2);
            a3 = fmaf(v.w, v.w, a3);
        }
        csq[tid] = (a0 + a1) + (a2 + a3);
    }
}

// ---------------- Phase A: persistent-codebook MFMA scores + top-2 + flag ----------------
__global__ __launch_bounds__(256, 1) void knn_mfma(const float* __restrict__ x,
                                                   const __bf16* __restrict__ cbB,
                                                   const float* __restrict__ csq_g,
                                                   int* __restrict__ out,
                                                   int* __restrict__ cnt,
                                                   int* __restrict__ wl) {
    __shared__ __bf16 sB[65536];                 // 128 KB: ENTIRE split codebook

    const int tid = threadIdx.x;
    const int wave = tid >> 6;                   // 0..3 (1 wave/SIMD)
    const int lane = tid & 63;
    const int rl = lane & 15;                    // m/n col within tile
    const int kg = lane >> 4;                    // k-group 0..3

    // ---- one-time B fill: wave w copies 32 KB (32 x 1 KB, linear) ----
    {
        const char* gsrc = (const char*)cbB + wave * 32768 + lane * 16;
        char* ldst = (char*)sB + wave * 32768;
#pragma unroll
        for (int i = 0; i < 32; ++i)
            __builtin_amdgcn_global_load_lds((gu32*)(gsrc + i * 1024),
                                             (lu32*)(ldst + i * 1024), 16, 0, 0);
    }

    float cs[16];
#pragma unroll
    for (int t = 0; t < 16; ++t) cs[t] = csq_g[t * 16 + rl];   // L1-hot, once

    // ---- 4 batches of 32 q per wave ----
#pragma unroll 1
    for (int bt = 0; bt < 4; ++bt) {
        const size_t q0 = (size_t)blockIdx.x * 512 + bt * 128 + wave * 32;

        // ---- A: load + split-convert this wave's 2 m-tiles into registers ----
        const float* xq = x + q0 * 128;
        bf16x8 ah[2][4], al[2][4];
#pragma unroll
        for (int m = 0; m < 2; ++m) {
#pragma unroll
            for (int kb = 0; kb < 4; ++kb) {
                const float* s = xq + (size_t)(m * 16 + rl) * 128 + kb * 32 + kg * 8;
                float4 f0 = *(const float4*)(s);
                float4 f1 = *(const float4*)(s + 4);
                float f[8] = {f0.x, f0.y, f0.z, f0.w, f1.x, f1.y, f1.z, f1.w};
                union { __bf16 h[8]; bf16x8 v; } ph, pl;
#pragma unroll
                for (int j = 0; j < 8; ++j) {
                    __bf16 hh = (__bf16)f[j];
                    ph.h[j] = hh;
                    pl.h[j] = (__bf16)(f[j] - (float)hh);
                }
                ah[m][kb] = ph.v;
                al[m][kb] = pl.v;
            }
        }

        floatx4 acc[2][16];
#pragma unroll
        for (int m = 0; m < 2; ++m)
#pragma unroll
            for (int t = 0; t < 16; ++t) acc[m][t] = (floatx4){0.f, 0.f, 0.f, 0.f};

        if (bt == 0) __syncthreads();            // B fill landed (vmcnt drain), once

        // ---- K-loop: pure LDS reads + MFMA, no barriers ----
        // element offset = kb*16384 + t*1024 + part*512 + lane*8
#pragma unroll
        for (int kb = 0; kb < 4; ++kb) {
            const __bf16* sbase = sB + kb * 16384 + lane * 8;
#pragma unroll
            for (int t = 0; t < 16; ++t) {
                bf16x8 bh = *(const bf16x8*)(sbase + t * 1024);
                bf16x8 bl = *(const bf16x8*)(sbase + t * 1024 + 512);
                acc[0][t] = MFMA16(ah[0][kb], bh, acc[0][t], 0, 0, 0);
                acc[1][t] = MFMA16(ah[1][kb], bh, acc[1][t], 0, 0, 0);
                acc[0][t] = MFMA16(al[0][kb], bh, acc[0][t], 0, 0, 0);
                acc[1][t] = MFMA16(al[1][kb], bh, acc[1][t], 0, 0, 0);
                acc[0][t] = MFMA16(ah[0][kb], bl, acc[0][t], 0, 0, 0);
                acc[1][t] = MFMA16(ah[1][kb], bl, acc[1][t], 0, 0, 0);
            }
        }

        // ---- epilogue: float-domain per-wave top-2 (ties -> refine) ----
#pragma unroll
        for (int m = 0; m < 2; ++m) {
#pragma unroll
            for (int r = 0; r < 4; ++r) {
                float bf = __builtin_inff(), sf = __builtin_inff();
                int bi = 0;
#pragma unroll
                for (int t = 0; t < 16; ++t) {
                    const float sc = fmaf(-2.0f, acc[m][t][r], cs[t]);
                    const bool lt = sc < bf;
                    sf = lt ? bf : fminf(sf, sc);
                    bf = lt ? sc : bf;
                    bi = lt ? (t * 16 + rl) : bi;
                }
#pragma unroll
                for (int d = 1; d < 16; d <<= 1) {
                    const float obf = __shfl_xor(bf, d);
                    const int   obi = __shfl_xor(bi, d);
                    const float osf = __shfl_xor(sf, d);
                    const bool lt = obf < bf;
                    const float loser = lt ? bf : obf;       // larger best
                    sf = fminf(fminf(sf, osf), loser);
                    bf = lt ? obf : bf;
                    bi = lt ? obi : bi;
                }
                if (rl == 0) {
                    const size_t qg = q0 + m * 16 + kg * 4 + r;
                    out[qg] = bi;
                    if (sf - bf < T_FLAG) {      // gap small (or tie) -> exact pass
                        int idx = atomicAdd(cnt, 1);
                        if (idx < WL_CAP) wl[idx] = (int)qg;
                    }
                }
            }
        }
    }
}

// ---------------- Phase B: exact fp32 rescan, block-per-query ----------------
__global__ __launch_bounds__(256) void knn_refine(const float* __restrict__ x,
                                                  const float* __restrict__ cb,
                                                  const float* __restrict__ csq_g,
                                                  const int* __restrict__ wl,
                                                  const int* __restrict__ cnt,
                                                  int* __restrict__ out) {
    __shared__ unsigned long long sP[4];
    const int tid = threadIdx.x;           // == code index k
    const int lane = tid & 63;
    const int wave = tid >> 6;

    int n = *cnt;
    if (n > WL_CAP) n = WL_CAP;
    const float mycsq = csq_g[tid];
    const float4* cr = (const float4*)(cb + (size_t)tid * 128);

    for (int i = blockIdx.x; i < n; i += gridDim.x) {
        const int q = wl[i];
        const float4* qr = (const float4*)(x + (size_t)q * 128);
        float a0 = 0.f, a1 = 0.f, a2 = 0.f, a3 = 0.f;
#pragma unroll 8
        for (int c4 = 0; c4 < 32; ++c4) {
            float4 qv = qr[c4];            // broadcast (same addr all lanes)
            float4 cv = cr[c4];
            a0 = fmaf(qv.x, cv.x, a0);
            a1 = fmaf(qv.y, cv.y, a1);
            a2 = fmaf(qv.z, cv.z, a2);
            a3 = fmaf(qv.w, cv.w, a3);
        }
        float dot = (a0 + a1) + (a2 + a3);
        float score = fmaf(-2.0f, dot, mycsq);
        unsigned long long key =
            ((unsigned long long)fmap(score) << 32) | (unsigned)tid;
#pragma unroll
        for (int d = 1; d < 64; d <<= 1) {
            unsigned long long o = __shfl_xor(key, d);
            key = o < key ? o : key;
        }
        if (lane == 0) sP[wave] = key;
        __syncthreads();
        if (tid == 0) {
            unsigned long long b = sP[0];
            unsigned long long o;
            o = sP[1]; b = o < b ? o : b;
            o = sP[2]; b = o < b ? o : b;
            o = sP[3]; b = o < b ? o : b;
            out[q] = (int)(unsigned)(b & 0xFFFFFFFFull);
        }
        __syncthreads();
    }
}

extern "C" void kernel_launch(void* const* d_in, const int* in_sizes, int n_in,
                              void* d_out, int out_size, void* d_ws, size_t ws_size,
                              hipStream_t stream) {
    const float* x = (const float*)d_in[0];
    const float* cb = (const float*)d_in[1];
    int* out = (int*)d_out;

    char* ws = (char*)d_ws;
    int* cnt = (int*)(ws + CNT_OFF);
    float* csq = (float*)(ws + CSQ_OFF);
    __bf16* cbB = (__bf16*)(ws + CBB_OFF);
    int* wl = (int*)(ws + WL_OFF);

    const int M = in_sizes[0] / 128;     // 131072

    knn_prep<<<32, 256, 0, stream>>>(cb, cbB, csq, cnt);
    knn_mfma<<<M / 512, 256, 0, stream>>>(x, cbB, csq, out, cnt, wl);
    knn_refine<<<240, 256, 0, stream>>>(x, cb, csq, wl, cnt, out);
}

// Round 8
// 121.949 us; speedup vs baseline: 1.2604x; 1.1015x over previous
//
#include <hip/hip_runtime.h>
#include <hip/hip_bf16.h>

// 1-NN VQ via split-bf16 MFMA + exact fp32 refinement.
//   score[q][k] = csq[k] - 2*dot(q,c_k); out = argmin_k (lowest-k tie-break).
// Phase 0 (knn_prep): codebook -> bf16 hi/lo fragment-ready cbB (kb-major) + csq.
// Phase A (knn_mfma): persistent codebook, 2 waves/SIMD spill-safe (r17).
//   r16 post-mortem: spill GONE (WRITE 48.6->0.5 MB) but dur only 62->51.5 us;
//   MfmaUtil 18 / VALUBusy 21 / Occupancy 9 / HBM 8% -- all pipes idle.
//   123k cyc/SIMD vs ~30k of pipe content: 4x exposed latency at 1 wave/SIMD
//   (ds_read waits, 3-deep MFMA dep chains ~32cyc, A-load latency, epilogue
//   shfl chain) with nothing to cover stalls.
//   r17: TLP=2 WITHOUT the r15 spill: halve wave tile to 16 q (m=1), keep all
//   16 n-tiles -> acc[16]=64 AGPR + ah/al[4]=32 + cs 16 + prefetch ~32 + temps
//   ~= 165 regs << 256 cap (r15 died at 128-arch budget; now 192-arch). 512
//   thr / 8 waves / 2 per SIMD, 128 KB LDS still forces 1 block/CU. Cost:
//   B ds_reads don't scale with q -> LDS traffic doubles (1 MB/batch/CU,
//   ~8.2k cyc floor) -- new structural floor ~14 us, 3.7x below r16 measured.
//   Everything else unchanged (unroll-1 bt loop, float top-2, one barrier).
//   Structure: whole split codebook in LDS once (16x gload_lds w=16/wave);
//   4 batches x 16 q/wave; K-loop pure ds_read_b128+MFMA, zero steady
//   barriers; dot ~= qh.ch+ql.ch+qh.cl (err ~1.9e-3); top-2 gap < T=0.004
//   -> worklist (ties -> refine exact pass, lowest-k tie-break there).
// Phase B (knn_refine): exact fp32 rescan (u64 keys, lowest-k tie-break).

typedef __bf16 bf16x8 __attribute__((ext_vector_type(8)));
typedef float  floatx4 __attribute__((ext_vector_type(4)));

#define MFMA16 __builtin_amdgcn_mfma_f32_16x16x32_bf16

#define CNT_OFF 0
#define CSQ_OFF 1024
#define CBB_OFF 4096
#define WL_OFF  (4096 + 131072)
#define WL_CAP  32768
#define T_FLAG  0.004f

typedef __attribute__((address_space(1))) const unsigned int gu32;
typedef __attribute__((address_space(3))) unsigned int lu32;

__device__ __forceinline__ unsigned fmap(float f) {
    unsigned u = __float_as_uint(f);
    return (u & 0x80000000u) ? ~u : (u | 0x80000000u);
}

// ---------------- Phase 0: codebook split, kb-major fragment layout, csq ----------------
// cbB element index = ((kb*16 + t)*2 + part)*512 + ln*8 + j   (= id*8 below)
//   kb = k-chunk 0..3; t = ntile 0..15; part: 0=hi 1=lo;
//   lane ln: n = t*16 + (ln&15), k = kb*32 + (ln>>4)*8 + j.
__global__ void knn_prep(const float* __restrict__ cb, __bf16* __restrict__ cbB,
                         float* __restrict__ csq, int* __restrict__ cnt) {
    const int tid = threadIdx.x;
    const int id = blockIdx.x * 256 + tid;       // 0..8191
    if (id == 0) *cnt = 0;
    const int ln = id & 63;
    const int part = (id >> 6) & 1;
    const int step = id >> 7;                    // kb*16 + t
    const int t4 = step & 15;
    const int kb = step >> 4;
    const int n = t4 * 16 + (ln & 15);
    const int k0 = kb * 32 + (ln >> 4) * 8;
    const float* src = cb + (size_t)n * 128 + k0;
    union { __bf16 h[8]; uint4 u; } p;
#pragma unroll
    for (int j = 0; j < 8; ++j) {
        float f = src[j];
        __bf16 hh = (__bf16)f;
        p.h[j] = (part == 0) ? hh : (__bf16)(f - (float)hh);
    }
    *(uint4*)(cbB + (size_t)id * 8) = p.u;

    if (blockIdx.x == 0) {
        const float4* row = (const float4*)(cb + (size_t)tid * 128);
        float a0 = 0.f, a1 = 0.f, a2 = 0.f, a3 = 0.f;
#pragma unroll 8
        for (int j = 0; j < 32; ++j) {
            float4 v = row[j];
            a0 = fmaf(v.x, v.x, a0);
            a1 = fmaf(v.y, v.y, a1);
            a2 = fmaf(v.z, v.z, a2);
            a3 = fmaf(v.w, v.w, a3);
        }
        csq[tid] = (a0 + a1) + (a2 + a3);
    }
}

// ---------------- Phase A: persistent-codebook MFMA scores + top-2 + flag ----------------
__global__ __launch_bounds__(512, 2) void knn_mfma(const float* __restrict__ x,
                                                   const __bf16* __restrict__ cbB,
                                                   const float* __restrict__ csq_g,
                                                   int* __restrict__ out,
                                                   int* __restrict__ cnt,
                                                   int* __restrict__ wl) {
    __shared__ __bf16 sB[65536];                 // 128 KB: ENTIRE split codebook

    const int tid = threadIdx.x;
    const int wave = tid >> 6;                   // 0..7 (2 waves/SIMD)
    const int lane = tid & 63;
    const int rl = lane & 15;                    // n col within tile
    const int kg = lane >> 4;                    // k-group 0..3

    // ---- one-time B fill: wave w copies 16 KB (16 x 1 KB, linear) ----
    {
        const char* gsrc = (const char*)cbB + wave * 16384 + lane * 16;
        char* ldst = (char*)sB + wave * 16384;
#pragma unroll
        for (int i = 0; i < 16; ++i)
            __builtin_amdgcn_global_load_lds((gu32*)(gsrc + i * 1024),
                                             (lu32*)(ldst + i * 1024), 16, 0, 0);
    }

    float cs[16];
#pragma unroll
    for (int t = 0; t < 16; ++t) cs[t] = csq_g[t * 16 + rl];   // L1-hot, once

    // ---- 4 batches of 16 q per wave ----
#pragma unroll 1
    for (int bt = 0; bt < 4; ++bt) {
        const size_t q0 = (size_t)blockIdx.x * 512 + bt * 128 + wave * 16;

        // ---- A: load + split-convert this wave's 1 m-tile into registers ----
        const float* xq = x + q0 * 128;
        bf16x8 ah[4], al[4];
#pragma unroll
        for (int kb = 0; kb < 4; ++kb) {
            const float* s = xq + (size_t)rl * 128 + kb * 32 + kg * 8;
            float4 f0 = *(const float4*)(s);
            float4 f1 = *(const float4*)(s + 4);
            float f[8] = {f0.x, f0.y, f0.z, f0.w, f1.x, f1.y, f1.z, f1.w};
            union { __bf16 h[8]; bf16x8 v; } ph, pl;
#pragma unroll
            for (int j = 0; j < 8; ++j) {
                __bf16 hh = (__bf16)f[j];
                ph.h[j] = hh;
                pl.h[j] = (__bf16)(f[j] - (float)hh);
            }
            ah[kb] = ph.v;
            al[kb] = pl.v;
        }

        floatx4 acc[16];
#pragma unroll
        for (int t = 0; t < 16; ++t) acc[t] = (floatx4){0.f, 0.f, 0.f, 0.f};

        if (bt == 0) __syncthreads();            // B fill landed (vmcnt drain), once

        // ---- K-loop: pure LDS reads + MFMA, no barriers ----
        // element offset = kb*16384 + t*1024 + part*512 + lane*8
#pragma unroll
        for (int kb = 0; kb < 4; ++kb) {
            const __bf16* sbase = sB + kb * 16384 + lane * 8;
#pragma unroll
            for (int t = 0; t < 16; ++t) {
                bf16x8 bh = *(const bf16x8*)(sbase + t * 1024);
                bf16x8 bl = *(const bf16x8*)(sbase + t * 1024 + 512);
                acc[t] = MFMA16(ah[kb], bh, acc[t], 0, 0, 0);
                acc[t] = MFMA16(al[kb], bh, acc[t], 0, 0, 0);
                acc[t] = MFMA16(ah[kb], bl, acc[t], 0, 0, 0);
            }
        }

        // ---- epilogue: float-domain per-wave top-2 (ties -> refine) ----
#pragma unroll
        for (int r = 0; r < 4; ++r) {
            float bf = __builtin_inff(), sf = __builtin_inff();
            int bi = 0;
#pragma unroll
            for (int t = 0; t < 16; ++t) {
                const float sc = fmaf(-2.0f, acc[t][r], cs[t]);
                const bool lt = sc < bf;
                sf = lt ? bf : fminf(sf, sc);
                bf = lt ? sc : bf;
                bi = lt ? (t * 16 + rl) : bi;
            }
#pragma unroll
            for (int d = 1; d < 16; d <<= 1) {
                const float obf = __shfl_xor(bf, d);
                const int   obi = __shfl_xor(bi, d);
                const float osf = __shfl_xor(sf, d);
                const bool lt = obf < bf;
                const float loser = lt ? bf : obf;           // larger best
                sf = fminf(fminf(sf, osf), loser);
                bf = lt ? obf : bf;
                bi = lt ? obi : bi;
            }
            if (rl == 0) {
                const size_t qg = q0 + kg * 4 + r;
                out[qg] = bi;
                if (sf - bf < T_FLAG) {          // gap small (or tie) -> exact pass
                    int idx = atomicAdd(cnt, 1);
                    if (idx < WL_CAP) wl[idx] = (int)qg;
                }
            }
        }
    }
}

// ---------------- Phase B: exact fp32 rescan, block-per-query ----------------
__global__ __launch_bounds__(256) void knn_refine(const float* __restrict__ x,
                                                  const float* __restrict__ cb,
                                                  const float* __restrict__ csq_g,
                                                  const int* __restrict__ wl,
                                                  const int* __restrict__ cnt,
                                                  int* __restrict__ out) {
    __shared__ unsigned long long sP[4];
    const int tid = threadIdx.x;           // == code index k
    const int lane = tid & 63;
    const int wave = tid >> 6;

    int n = *cnt;
    if (n > WL_CAP) n = WL_CAP;
    const float mycsq = csq_g[tid];
    const float4* cr = (const float4*)(cb + (size_t)tid * 128);

    for (int i = blockIdx.x; i < n; i += gridDim.x) {
        const int q = wl[i];
        const float4* qr = (const float4*)(x + (size_t)q * 128);
        float a0 = 0.f, a1 = 0.f, a2 = 0.f, a3 = 0.f;
#pragma unroll 8
        for (int c4 = 0; c4 < 32; ++c4) {
            float4 qv = qr[c4];            // broadcast (same addr all lanes)
            float4 cv = cr[c4];
            a0 = fmaf(qv.x, cv.x, a0);
            a1 = fmaf(qv.y, cv.y, a1);
            a2 = fmaf(qv.z, cv.z, a2);
            a3 = fmaf(qv.w, cv.w, a3);
        }
        float dot = (a0 + a1) + (a2 + a3);
        float score = fmaf(-2.0f, dot, mycsq);
        unsigned long long key =
            ((unsigned long long)fmap(score) << 32) | (unsigned)tid;
#pragma unroll
        for (int d = 1; d < 64; d <<= 1) {
            unsigned long long o = __shfl_xor(key, d);
            key = o < key ? o : key;
        }
        if (lane == 0) sP[wave] = key;
        __syncthreads();
        if (tid == 0) {
            unsigned long long b = sP[0];
            unsigned long long o;
            o = sP[1]; b = o < b ? o : b;
            o = sP[2]; b = o < b ? o : b;
            o = sP[3]; b = o < b ? o : b;
            out[q] = (int)(unsigned)(b & 0xFFFFFFFFull);
        }
        __syncthreads();
    }
}

extern "C" void kernel_launch(void* const* d_in, const int* in_sizes, int n_in,
                              void* d_out, int out_size, void* d_ws, size_t ws_size,
                              hipStream_t stream) {
    const float* x = (const float*)d_in[0];
    const float* cb = (const float*)d_in[1];
    int* out = (int*)d_out;

    char* ws = (char*)d_ws;
    int* cnt = (int*)(ws + CNT_OFF);
    float* csq = (float*)(ws + CSQ_OFF);
    __bf16* cbB = (__bf16*)(ws + CBB_OFF);
    int* wl = (int*)(ws + WL_OFF);

    const int M = in_sizes[0] / 128;     // 131072

    knn_prep<<<32, 256, 0, stream>>>(cb, cbB, csq, cnt);
    knn_mfma<<<M / 512, 512, 0, stream>>>(x, cbB, csq, out, cnt, wl);
    knn_refine<<<240, 256, 0, stream>>>(x, cb, csq, wl, cnt, out);
}